// Round 5
// baseline (210.768 us; speedup 1.0000x reference)
//
#include <hip/hip_runtime.h>
#include <hip/hip_bf16.h>

#define E_NUM 64
#define IN_SZ 512
#define OUT_SZ 512
#define N_TOK 131072
#define CAP 3072

#define BM 128
#define BN 512
#define BK 32
#define THREADS 512
#define RT_MAX 24   // CAP/BM
#define JT 16       // IN_SZ/BK
#define NWG (E_NUM * RT_MAX)

typedef __attribute__((ext_vector_type(8))) short short8;
typedef __attribute__((ext_vector_type(4))) float f32x4;

__device__ inline unsigned short f2bf(float f) {
    unsigned int u = __float_as_uint(f);
    unsigned int r = (u + 0x7FFF + ((u >> 16) & 1)) >> 16;
    return (unsigned short)r;
}

#define GLOAD_LDS16(g, l)                                                     \
    __builtin_amdgcn_global_load_lds(                                         \
        (const __attribute__((address_space(1))) void*)(g),                   \
        (__attribute__((address_space(3))) void*)(l), 16, 0, 0)

// ---------------- kernel 1: exclusive prefix sum of expert sizes ----------
__global__ void offsets_kernel(const int* __restrict__ sizes, int* __restrict__ offs) {
    int e = threadIdx.x;
    int s = 0;
    for (int i = 0; i < e; ++i) s += sizes[i];
    offs[e] = s;
}

// ---------------- kernel 2: W [E][K][N] f32 -> WT [E][N][K] bf16 ----------
__global__ __launch_bounds__(256) void prep_wt(const float* __restrict__ W,
                                               unsigned short* __restrict__ WT) {
    __shared__ float t[32][33];
    int k0 = blockIdx.x * 32, n0 = blockIdx.y * 32, e = blockIdx.z;
    const float* We = W + (size_t)e * IN_SZ * OUT_SZ;
    int tid = threadIdx.x;
    int r = tid >> 3, c4 = (tid & 7) * 4;
    float4 v = *(const float4*)(We + (size_t)(k0 + r) * OUT_SZ + n0 + c4);
    t[r][c4 + 0] = v.x; t[r][c4 + 1] = v.y; t[r][c4 + 2] = v.z; t[r][c4 + 3] = v.w;
    __syncthreads();
    ushort4 o;
    o.x = f2bf(t[c4 + 0][r]);
    o.y = f2bf(t[c4 + 1][r]);
    o.z = f2bf(t[c4 + 2][r]);
    o.w = f2bf(t[c4 + 3][r]);
    unsigned short* O = WT + (size_t)e * IN_SZ * OUT_SZ + (size_t)(n0 + r) * IN_SZ + k0 + c4;
    *(ushort4*)O = o;
}

// ---------------- kernel 3: grouped GEMM, BN=512 (A read once) ------------
// Swizzle (verified 0-conflict R2/R4): 16B-slot index ^= (row>>1)&3 within
// each 64B k-row. A: ds_write + ds_read. B: pre-swizzled GLOBAL source for
// linear global_load_lds + same XOR on ds_read (involution, rule #21).
// 3-buffer counted-vmcnt pipeline; per-iter VMEM = 2 A-loads + 4 gload_lds.
__global__ __launch_bounds__(THREADS, 1) void gemm_moe(
    const float* __restrict__ A, const int* __restrict__ sizes,
    const unsigned short* __restrict__ WT, const int* __restrict__ offs,
    float* __restrict__ out)
{
    // bijective XCD swizzle: 1536 blocks, 192 per XCD chunk; consecutive wg
    // on one XCD = consecutive row-tiles of one expert -> B-tile L2 reuse.
    int b0 = blockIdx.x;
    int wg = (b0 & 7) * (NWG / 8) + (b0 >> 3);
    int rt = wg % RT_MAX;
    int e  = wg / RT_MAX;

    int size_e = sizes[e];
    int rows0 = rt * BM;
    if (rows0 >= size_e) return;
    int off_e = offs[e];
    int rows_rem = size_e - rows0;                      // >= 1
    int maxr = (rows_rem < BM ? rows_rem : BM) - 1;

    __shared__ unsigned short lsA[3][BM * BK];   // 3 x 8 KB
    __shared__ unsigned short lsB[3][BN * BK];   // 3 x 32 KB

    int tid = threadIdx.x, l = tid & 63, w = tid >> 6;
    const char* WTe = (const char*)(WT + (size_t)e * IN_SZ * OUT_SZ);
    const float* Abase = A + (size_t)(off_e + rows0) * IN_SZ;

    // ---- A staging geometry (i<2: idx = tid + 512*i, fully coalesced) ----
    const float* ap[2];
    int aw[2];
    #pragma unroll
    for (int i = 0; i < 2; ++i) {
        int idx = tid + THREADS * i;
        int row = idx >> 3, c4 = idx & 7;
        int gr = row <= maxr ? row : maxr;
        ap[i] = Abase + (size_t)gr * IN_SZ + c4 * 4;
        aw[i] = row * 64 + ((c4 * 8) ^ (((row >> 1) & 3) << 4));
    }
    // ---- B staging geometry (chunks c = w*4+i, c<32; LDS row c*16+l>>2) --
    const char* gB[4];
    #pragma unroll
    for (int i = 0; i < 4; ++i) {
        int c = w * 4 + i;
        int n = c * 16 + (l >> 2);
        int csrc = ((l & 3) * 16) ^ (((l >> 3) & 3) << 4);
        gB[i] = WTe + (size_t)n * (IN_SZ * 2) + csrc;
    }

    float4 ar[2][2];   // 2 in-flight A register sets

    auto loadA = [&](int kt, int p) {
        #pragma unroll
        for (int i = 0; i < 2; ++i)
            ar[p][i] = *(const float4*)(ap[i] + kt * BK);
    };
    auto writeA = [&](int buf, int p) {
        #pragma unroll
        for (int i = 0; i < 2; ++i) {
            ushort4 pk;
            pk.x = f2bf(ar[p][i].x); pk.y = f2bf(ar[p][i].y);
            pk.z = f2bf(ar[p][i].z); pk.w = f2bf(ar[p][i].w);
            *(ushort4*)((char*)&lsA[buf][0] + aw[i]) = pk;
        }
    };
    auto stageB = [&](int buf, int kt) {
        #pragma unroll
        for (int i = 0; i < 4; ++i)
            GLOAD_LDS16(gB[i] + kt * 64, &lsB[buf][(w * 4 + i) * 512]);
    };

    int wm = (w >> 2) * 64, wn = (w & 3) * 128;
    int lrow = l & 15;
    int cb = ((l >> 4) * 16) ^ (((l >> 1) & 3) << 4);

    f32x4 acc[4][8] = {};

    #define FRAGS_AND_MFMA(buf)                                               \
        {                                                                     \
            const char* pA = (const char*)&lsA[buf][0];                       \
            const char* pB = (const char*)&lsB[buf][0];                       \
            short8 af[4];                                                     \
            _Pragma("unroll")                                                 \
            for (int m = 0; m < 4; ++m)                                       \
                af[m] = *(const short8*)(pA + (wm + m * 16 + lrow) * 64 + cb);\
            short8 bfr[8];                                                    \
            _Pragma("unroll")                                                 \
            for (int n = 0; n < 8; ++n)                                       \
                bfr[n] = *(const short8*)(pB + (wn + n * 16 + lrow) * 64 + cb);\
            asm volatile("s_waitcnt lgkmcnt(0)" ::: "memory");                \
            __builtin_amdgcn_sched_barrier(0);                                \
            __builtin_amdgcn_s_setprio(1);                                    \
            _Pragma("unroll")                                                 \
            for (int m = 0; m < 4; ++m)                                       \
                _Pragma("unroll")                                             \
                for (int n = 0; n < 8; ++n)                                   \
                    acc[m][n] = __builtin_amdgcn_mfma_f32_16x16x32_bf16(      \
                        af[m], bfr[n], acc[m][n], 0, 0, 0);                   \
            __builtin_amdgcn_s_setprio(0);                                    \
        }

    // ---- prologue: tiles 0,1 staged; A0 written ----
    loadA(0, 0); stageB(0, 0);
    loadA(1, 1); stageB(1, 1);
    writeA(0, 0);                                   // implicit wait on A0 loads
    asm volatile("s_waitcnt vmcnt(6)" ::: "memory");   // B0 landed; A1,B1 fly
    __builtin_amdgcn_sched_barrier(0);
    asm volatile("s_waitcnt lgkmcnt(0)" ::: "memory"); // A0 ds_writes visible
    __builtin_amdgcn_sched_barrier(0);
    __builtin_amdgcn_s_barrier();
    __builtin_amdgcn_sched_barrier(0);

    // ---- main loop, fully unrolled (all buf/set indices static) ----
    #pragma unroll
    for (int j = 0; j < JT; ++j) {
        if (j + 2 < JT) {
            loadA(j + 2, (j + 2) & 1);
            stageB((j + 2) % 3, j + 2);
        }
        FRAGS_AND_MFMA(j % 3);
        if (j + 1 < JT)
            writeA((j + 1) % 3, (j + 1) & 1);
        if (j < JT - 1) {
            if (j < JT - 2) {
                asm volatile("s_waitcnt vmcnt(6)" ::: "memory");
            } else {
                asm volatile("s_waitcnt vmcnt(0)" ::: "memory");
            }
            __builtin_amdgcn_sched_barrier(0);
            asm volatile("s_waitcnt lgkmcnt(0)" ::: "memory");
            __builtin_amdgcn_sched_barrier(0);
            __builtin_amdgcn_s_barrier();
            __builtin_amdgcn_sched_barrier(0);
        }
    }

    // epilogue: C/D layout col = lane&15, row = (lane>>4)*4 + reg
    float* outb = out + (size_t)(off_e + rows0) * OUT_SZ + wn;
    #pragma unroll
    for (int m = 0; m < 4; ++m) {
        #pragma unroll
        for (int j = 0; j < 4; ++j) {
            int rl = wm + m * 16 + (l >> 4) * 4 + j;
            if (rl < rows_rem) {
                float* po = outb + (size_t)rl * OUT_SZ + lrow;
                #pragma unroll
                for (int n = 0; n < 8; ++n)
                    po[n * 16] = acc[m][n][j];
            }
        }
    }
}

extern "C" void kernel_launch(void* const* d_in, const int* in_sizes, int n_in,
                              void* d_out, int out_size, void* d_ws, size_t ws_size,
                              hipStream_t stream) {
    const float* A      = (const float*)d_in[0];
    const int* sizes    = (const int*)d_in[1];
    const float* W      = (const float*)d_in[2];
    float* out          = (float*)d_out;

    unsigned short* WT  = (unsigned short*)d_ws;                       // 32 MB
    int* offs           = (int*)((char*)d_ws + (size_t)E_NUM * IN_SZ * OUT_SZ * 2);

    offsets_kernel<<<1, E_NUM, 0, stream>>>(sizes, offs);
    prep_wt<<<dim3(IN_SZ / 32, OUT_SZ / 32, E_NUM), 256, 0, stream>>>(W, WT);
    gemm_moe<<<NWG, THREADS, 0, stream>>>(A, sizes, WT, offs, out);
}